// Round 6
// baseline (72.791 us; speedup 1.0000x reference)
//
#include <hip/hip_runtime.h>
#include <hip/hip_bf16.h>

typedef __bf16 bf16x8 __attribute__((ext_vector_type(8)));
typedef float  f32x4  __attribute__((ext_vector_type(4)));

#define B_ROWS 8192
#define IN_DIM 256
#define OUT_DIM 32
#define NCLS 50
#define INV_T (1.0f / 0.6f)

#define CVT_BLOCKS 1024  // x cvt: 8192*256 / (256*8)
#define PG_BLOCKS 400    // partial gamma: 50 classes * 8 o-quads
#define MTILES 128       // 8192 / 64 rows per block

__device__ __forceinline__ void gload_lds16(const void* g, void* l) {
    __builtin_amdgcn_global_load_lds(
        (const __attribute__((address_space(1))) void*)g,
        (__attribute__((address_space(3))) void*)l, 16, 0, 0);
}

// k1: blocks [0,1024) convert x f32->bf16; blocks [1024,1424) partial gamma:
// partial[c*8+q][i] = sum_{o in q*4..q*4+3} |W[c,o,i]|
__global__ __launch_bounds__(256) void k1_cvt_partial(const float* __restrict__ x,
                                                      const float* __restrict__ w,
                                                      __bf16* __restrict__ xb,
                                                      float* __restrict__ partial) {
    int bid = blockIdx.x;
    if (bid < CVT_BLOCKS) {
        int i = (bid * 256 + threadIdx.x) * 8;
        float4 v0 = *reinterpret_cast<const float4*>(x + i);
        float4 v1 = *reinterpret_cast<const float4*>(x + i + 4);
        bf16x8 r;
        r[0] = (__bf16)v0.x; r[1] = (__bf16)v0.y; r[2] = (__bf16)v0.z; r[3] = (__bf16)v0.w;
        r[4] = (__bf16)v1.x; r[5] = (__bf16)v1.y; r[6] = (__bf16)v1.z; r[7] = (__bf16)v1.w;
        *reinterpret_cast<bf16x8*>(xb + i) = r;
    } else {
        int p = bid - CVT_BLOCKS;        // 0..399
        int c = p >> 3, q = p & 7;
        int i = threadIdx.x;
        const float* wp = w + ((size_t)(c * OUT_DIM + q * 4)) * IN_DIM + i;
        float g = fabsf(wp[0]) + fabsf(wp[IN_DIM]) + fabsf(wp[2 * IN_DIM]) + fabsf(wp[3 * IN_DIM]);
        partial[(size_t)p * IN_DIM + i] = g;
    }
}

// k2: 200 blocks; block = (class c, o-oct). Recompute alpha for c (cheap),
// scale 8 o-rows of W into bf16 W'.
__global__ __launch_bounds__(256) void k2_alpha_scale(const float* __restrict__ partial,
                                                      const float* __restrict__ w,
                                                      __bf16* __restrict__ wb) {
    int blk = blockIdx.x;        // 0..199
    int c = blk >> 2;
    int o0 = (blk & 3) * 8;
    int i = threadIdx.x;
    float g = 0.f;
#pragma unroll
    for (int q = 0; q < 8; ++q)
        g += partial[(size_t)(c * 8 + q) * IN_DIM + i];
    float m = g;
#pragma unroll
    for (int s = 1; s < 64; s <<= 1) m = fmaxf(m, __shfl_xor(m, s));
    __shared__ float wm[4];
    if ((threadIdx.x & 63) == 0) wm[threadIdx.x >> 6] = m;
    __syncthreads();
    m = fmaxf(fmaxf(wm[0], wm[1]), fmaxf(wm[2], wm[3]));
    float an = __expf((g - m) * INV_T);
    const float* wr = w + ((size_t)c * OUT_DIM + o0) * IN_DIM + i;
    __bf16* wo = wb + ((size_t)c * OUT_DIM + o0) * IN_DIM + i;
#pragma unroll
    for (int o = 0; o < 8; ++o)
        wo[o * IN_DIM] = (__bf16)(wr[o * IN_DIM] * an);
}

// GEMM: out[b, c, o] = sum_i xb[b,i]*wb[c,o,i] + bias[c,o]
// grid = c*128 + mtile (mtile = 64 rows). Block = 4 INDEPENDENT waves.
// Wave w: stages its 16 rows of x into LDS via global_load_lds (async, no
// VGPRs), W' class-fragments register-resident, swizzled ds_read + 16 MFMA.
// LDS swizzle: physical slot s holds logical slot s^(row&15) (both-sides XOR).
__global__ __launch_bounds__(256, 2) void gemm(const __bf16* __restrict__ xb,
                                               const __bf16* __restrict__ wb,
                                               const float* __restrict__ bias,
                                               float* __restrict__ out) {
    __shared__ bf16x8 Alds_v[64 * 32];   // 64 rows * 512 B = 32 KB, 16B-aligned
    char* alds = (char*)Alds_v;

    int bid = blockIdx.x;
    int c = bid >> 7;            // 0..49
    int mtile = bid & (MTILES - 1);
    int row0 = mtile * 64;
    int lane = threadIdx.x & 63;
    int w4 = threadIdx.x >> 6;   // wave 0..3
    int l15 = lane & 15;
    int g = lane >> 4;

    // --- stage this wave's 16 rows (rows 16*w4 .. +15 of tile) ---
    const char* tile = (const char*)(xb + (size_t)row0 * IN_DIM);
    int lrow = lane >> 5;        // 0/1
    int s = lane & 31;           // physical 16B slot
#pragma unroll
    for (int il = 0; il < 8; ++il) {
        int row = 16 * w4 + 2 * il + lrow;
        const void* src = tile + (size_t)row * 512 + ((s ^ (row & 15)) * 16);
        void* dst = alds + (16 * w4 + 2 * il) * 512;   // wave-uniform base
        gload_lds16(src, dst);
    }

    // --- W' fragments: lane holds W'[c][o=l15(+16)][k=g*8+j+32*kk] ---
    const __bf16* wp = wb + ((size_t)c * OUT_DIM + l15) * IN_DIM + g * 8;
    bf16x8 W[16];
#pragma unroll
    for (int kk = 0; kk < 8; ++kk) {
        W[kk]     = *reinterpret_cast<const bf16x8*>(wp + kk * 32);
        W[8 + kk] = *reinterpret_cast<const bf16x8*>(wp + 16 * IN_DIM + kk * 32);
    }
#pragma unroll
    for (int kk = 0; kk < 16; ++kk)
        asm volatile("" : "+v"(W[kk]));

    float4 bv0 = *reinterpret_cast<const float4*>(bias + c * OUT_DIM + g * 4);
    float4 bv1 = *reinterpret_cast<const float4*>(bias + c * OUT_DIM + 16 + g * 4);

    // wait for staging (and W) to land; fence so ds_reads can't hoist above
    asm volatile("s_waitcnt vmcnt(0)" ::: "memory");
    __builtin_amdgcn_sched_barrier(0);

    f32x4 acc0 = {bv0.x, bv0.y, bv0.z, bv0.w};
    f32x4 acc1 = {bv1.x, bv1.y, bv1.z, bv1.w};
    int arow = 16 * w4 + l15;
#pragma unroll
    for (int kk = 0; kk < 8; ++kk) {
        int slot = (4 * kk + g) ^ l15;   // logical -> physical (involution)
        bf16x8 a = *reinterpret_cast<const bf16x8*>(alds + (size_t)arow * 512 + slot * 16);
        acc0 = __builtin_amdgcn_mfma_f32_16x16x32_bf16(W[kk],     a, acc0, 0, 0, 0);
        acc1 = __builtin_amdgcn_mfma_f32_16x16x32_bf16(W[8 + kk], a, acc1, 0, 0, 0);
    }

    float* op = out + (size_t)(row0 + arow) * (NCLS * OUT_DIM) + c * OUT_DIM + g * 4;
    *reinterpret_cast<f32x4*>(op) = acc0;
    *reinterpret_cast<f32x4*>(op + 16) = acc1;
}

extern "C" void kernel_launch(void* const* d_in, const int* in_sizes, int n_in,
                              void* d_out, int out_size, void* d_ws, size_t ws_size,
                              hipStream_t stream) {
    const float* x    = (const float*)d_in[0];
    const float* w    = (const float*)d_in[1];
    const float* bias = (const float*)d_in[2];
    float* out = (float*)d_out;

    __bf16* xb     = (__bf16*)d_ws;                                   // 4 MB
    __bf16* wb     = xb + (size_t)B_ROWS * IN_DIM;                    // 0.8 MB
    float*  partial = (float*)(wb + (size_t)NCLS * OUT_DIM * IN_DIM); // 400 KB

    k1_cvt_partial<<<CVT_BLOCKS + PG_BLOCKS, 256, 0, stream>>>(x, w, xb, partial);
    k2_alpha_scale<<<200, 256, 0, stream>>>(partial, w, wb);
    gemm<<<NCLS * MTILES, 256, 0, stream>>>(xb, wb, bias, out);
}

// Round 7
// 34.924 us; speedup vs baseline: 2.0843x; 2.0843x over previous
//
#include <hip/hip_runtime.h>
#include <hip/hip_bf16.h>

typedef __bf16 bf16x8 __attribute__((ext_vector_type(8)));
typedef float  f32x4  __attribute__((ext_vector_type(4)));

#define B_ROWS 8192
#define IN_DIM 256
#define OUT_DIM 32
#define NCLS 50
#define INV_T (1.0f / 0.6f)

#define CVT_BLOCKS 1024  // x cvt: 8192*256 / (256*8)
#define PG_BLOCKS 400    // partial gamma: 50 classes * 8 o-quads
#define ROWTILES 16      // 8192 / 512 rows per block
#define NCHUNK 8         // 128 rows/wave / 16

__device__ __forceinline__ void gload_lds16(const void* g, void* l) {
    __builtin_amdgcn_global_load_lds(
        (const __attribute__((address_space(1))) void*)g,
        (__attribute__((address_space(3))) void*)l, 16, 0, 0);
}

// k1: blocks [0,1024) convert x f32->bf16; blocks [1024,1424) partial gamma.
__global__ __launch_bounds__(256) void k1_cvt_partial(const float* __restrict__ x,
                                                      const float* __restrict__ w,
                                                      __bf16* __restrict__ xb,
                                                      float* __restrict__ partial) {
    int bid = blockIdx.x;
    if (bid < CVT_BLOCKS) {
        int i = (bid * 256 + threadIdx.x) * 8;
        float4 v0 = *reinterpret_cast<const float4*>(x + i);
        float4 v1 = *reinterpret_cast<const float4*>(x + i + 4);
        bf16x8 r;
        r[0] = (__bf16)v0.x; r[1] = (__bf16)v0.y; r[2] = (__bf16)v0.z; r[3] = (__bf16)v0.w;
        r[4] = (__bf16)v1.x; r[5] = (__bf16)v1.y; r[6] = (__bf16)v1.z; r[7] = (__bf16)v1.w;
        *reinterpret_cast<bf16x8*>(xb + i) = r;
    } else {
        int p = bid - CVT_BLOCKS;        // 0..399
        int c = p >> 3, q = p & 7;
        int i = threadIdx.x;
        const float* wp = w + ((size_t)(c * OUT_DIM + q * 4)) * IN_DIM + i;
        float g = fabsf(wp[0]) + fabsf(wp[IN_DIM]) + fabsf(wp[2 * IN_DIM]) + fabsf(wp[3 * IN_DIM]);
        partial[(size_t)p * IN_DIM + i] = g;
    }
}

// k2: 200 blocks; block = (class c, o-oct). Recompute alpha, scale 8 o-rows.
__global__ __launch_bounds__(256) void k2_alpha_scale(const float* __restrict__ partial,
                                                      const float* __restrict__ w,
                                                      __bf16* __restrict__ wb) {
    int blk = blockIdx.x;        // 0..199
    int c = blk >> 2;
    int o0 = (blk & 3) * 8;
    int i = threadIdx.x;
    float g = 0.f;
#pragma unroll
    for (int q = 0; q < 8; ++q)
        g += partial[(size_t)(c * 8 + q) * IN_DIM + i];
    float m = g;
#pragma unroll
    for (int s = 1; s < 64; s <<= 1) m = fmaxf(m, __shfl_xor(m, s));
    __shared__ float wm[4];
    if ((threadIdx.x & 63) == 0) wm[threadIdx.x >> 6] = m;
    __syncthreads();
    m = fmaxf(fmaxf(wm[0], wm[1]), fmaxf(wm[2], wm[3]));
    float an = __expf((g - m) * INV_T);
    const float* wr = w + ((size_t)c * OUT_DIM + o0) * IN_DIM + i;
    __bf16* wo = wb + ((size_t)c * OUT_DIM + o0) * IN_DIM + i;
#pragma unroll
    for (int o = 0; o < 8; ++o)
        wo[o * IN_DIM] = (__bf16)(wr[o * IN_DIM] * an);
}

// GEMM: out[b, c, o] = sum_i xb[b,i]*wb[c,o,i] + bias[c,o]
// grid = 50 classes * 16 row-tiles; block = 4 waves, 512 rows, ONE class.
// W' staged once via global_load_lds -> broadcast ds_read -> pinned regs
// (amortized over 8 chunks/wave). A double-buffered per wave with counted
// vmcnt(8) so next chunk's staging stays in flight during MFMA.
// LDS swizzle (both-sides): phys 16B-slot p of row r holds logical p^(r&15).
__global__ __launch_bounds__(256, 2) void gemm(const __bf16* __restrict__ xb,
                                               const __bf16* __restrict__ wb,
                                               const float* __restrict__ bias,
                                               float* __restrict__ out) {
    __shared__ __align__(16) char lds[16384 + 4 * 2 * 8192];  // W 16K + 4 waves * 2 bufs * 8K

    int bid = blockIdx.x;
    int c = bid >> 4;            // 0..49
    int rt = bid & (ROWTILES - 1);
    int row0 = rt * 512;
    int lane = threadIdx.x & 63;
    int w4 = threadIdx.x >> 6;
    int l15 = lane & 15;
    int g = lane >> 4;

    char* Wlds = lds;
    char* Abuf0 = lds + 16384 + w4 * 16384;
    char* Abuf1 = Abuf0 + 8192;

    // --- stage A chunk 0 (wave-private 16 rows = 8 KB) ---
    const char* arows = (const char*)(xb + (size_t)(row0 + w4 * 128) * IN_DIM);
    int s31 = lane & 31;
    int lr = lane >> 5;          // 0/1
#define STAGE_A(BUF, CHUNK)                                                       \
    _Pragma("unroll") for (int il = 0; il < 8; ++il) {                            \
        int r = (CHUNK) * 16 + 2 * il + lr;                                       \
        gload_lds16(arows + (size_t)r * 512 + ((s31 ^ (r & 15)) * 16),            \
                    (BUF) + il * 1024);                                           \
    }
    STAGE_A(Abuf0, 0)

    // --- stage W' (16 KB, all 256 threads, 4 instrs) ---
    const char* wsrc = (const char*)(wb + (size_t)c * OUT_DIM * IN_DIM);
#pragma unroll
    for (int j = 0; j < 4; ++j) {
        int row = j * 8 + w4 * 2 + lr;
        gload_lds16(wsrc + (size_t)row * 512 + ((s31 ^ (row & 15)) * 16),
                    Wlds + j * 4096 + w4 * 1024);
    }

    asm volatile("s_waitcnt vmcnt(0)" ::: "memory");
    __syncthreads();
    __builtin_amdgcn_sched_barrier(0);

    // --- W' -> regs (swizzled broadcast ds_read) ---
    bf16x8 W[16];
#pragma unroll
    for (int kk = 0; kk < 8; ++kk) {
        int slot = (4 * kk + g) ^ l15;
        W[kk]     = *reinterpret_cast<const bf16x8*>(Wlds + (size_t)l15 * 512 + slot * 16);
        W[8 + kk] = *reinterpret_cast<const bf16x8*>(Wlds + (size_t)(16 + l15) * 512 + slot * 16);
    }
#pragma unroll
    for (int kk = 0; kk < 16; ++kk)
        asm volatile("" : "+v"(W[kk]));

    float4 bv0 = *reinterpret_cast<const float4*>(bias + c * OUT_DIM + g * 4);
    float4 bv1 = *reinterpret_cast<const float4*>(bias + c * OUT_DIM + 16 + g * 4);

    float* orow = out + (size_t)(row0 + w4 * 128 + l15) * (NCLS * OUT_DIM) + c * OUT_DIM + g * 4;

    // --- main loop: 8 chunks of 16 rows ---
#pragma unroll
    for (int k = 0; k < NCHUNK; ++k) {
        char* cur = (k & 1) ? Abuf1 : Abuf0;
        char* nxt = (k & 1) ? Abuf0 : Abuf1;
        if (k + 1 < NCHUNK) {
            STAGE_A(nxt, k + 1)
            asm volatile("s_waitcnt vmcnt(8)" ::: "memory");
        } else {
            asm volatile("s_waitcnt vmcnt(0)" ::: "memory");
        }
        __builtin_amdgcn_sched_barrier(0);

        f32x4 acc0 = {bv0.x, bv0.y, bv0.z, bv0.w};
        f32x4 acc1 = {bv1.x, bv1.y, bv1.z, bv1.w};
#pragma unroll
        for (int kk = 0; kk < 8; ++kk) {
            int slot = (4 * kk + g) ^ l15;
            bf16x8 a = *reinterpret_cast<const bf16x8*>(cur + (size_t)l15 * 512 + slot * 16);
            acc0 = __builtin_amdgcn_mfma_f32_16x16x32_bf16(W[kk],     a, acc0, 0, 0, 0);
            acc1 = __builtin_amdgcn_mfma_f32_16x16x32_bf16(W[8 + kk], a, acc1, 0, 0, 0);
        }
        float* op = orow + (size_t)k * 16 * (NCLS * OUT_DIM);
        *reinterpret_cast<f32x4*>(op) = acc0;
        *reinterpret_cast<f32x4*>(op + 16) = acc1;
    }
#undef STAGE_A
}

extern "C" void kernel_launch(void* const* d_in, const int* in_sizes, int n_in,
                              void* d_out, int out_size, void* d_ws, size_t ws_size,
                              hipStream_t stream) {
    const float* x    = (const float*)d_in[0];
    const float* w    = (const float*)d_in[1];
    const float* bias = (const float*)d_in[2];
    float* out = (float*)d_out;

    __bf16* xb      = (__bf16*)d_ws;                                   // 4 MB
    __bf16* wb      = xb + (size_t)B_ROWS * IN_DIM;                    // 0.8 MB
    float*  partial = (float*)(wb + (size_t)NCLS * OUT_DIM * IN_DIM);  // 400 KB

    k1_cvt_partial<<<CVT_BLOCKS + PG_BLOCKS, 256, 0, stream>>>(x, w, xb, partial);
    k2_alpha_scale<<<200, 256, 0, stream>>>(partial, w, wb);
    gemm<<<NCLS * ROWTILES, 256, 0, stream>>>(xb, wb, bias, out);
}

// Round 9
// 30.665 us; speedup vs baseline: 2.3737x; 1.1389x over previous
//
#include <hip/hip_runtime.h>
#include <hip/hip_bf16.h>

typedef __bf16 bf16x8 __attribute__((ext_vector_type(8)));
typedef float  f32x4  __attribute__((ext_vector_type(4)));

#define B_ROWS 8192
#define IN_DIM 256
#define OUT_DIM 32
#define NCLS 50
#define INV_T (1.0f / 0.6f)

#define CVT_BLOCKS 1024  // x cvt: 8192*256 / (256*8)
#define PG_BLOCKS 400    // partial gamma: 50 classes * 8 o-quads
#define ROWTILES 16      // 8192 / 512 rows per block
#define NCHUNK 8         // 128 rows/wave / 16

__device__ __forceinline__ void gload_lds16(const void* g, void* l) {
    __builtin_amdgcn_global_load_lds(
        (const __attribute__((address_space(1))) void*)g,
        (__attribute__((address_space(3))) void*)l, 16, 0, 0);
}

// k1: blocks [0,1024) convert x f32->bf16; blocks [1024,1424) partial gamma.
__global__ __launch_bounds__(256) void k1_cvt_partial(const float* __restrict__ x,
                                                      const float* __restrict__ w,
                                                      __bf16* __restrict__ xb,
                                                      float* __restrict__ partial) {
    int bid = blockIdx.x;
    if (bid < CVT_BLOCKS) {
        int i = (bid * 256 + threadIdx.x) * 8;
        float4 v0 = *reinterpret_cast<const float4*>(x + i);
        float4 v1 = *reinterpret_cast<const float4*>(x + i + 4);
        bf16x8 r;
        r[0] = (__bf16)v0.x; r[1] = (__bf16)v0.y; r[2] = (__bf16)v0.z; r[3] = (__bf16)v0.w;
        r[4] = (__bf16)v1.x; r[5] = (__bf16)v1.y; r[6] = (__bf16)v1.z; r[7] = (__bf16)v1.w;
        *reinterpret_cast<bf16x8*>(xb + i) = r;
    } else {
        int p = bid - CVT_BLOCKS;        // 0..399
        int c = p >> 3, q = p & 7;
        int i = threadIdx.x;
        const float* wp = w + ((size_t)(c * OUT_DIM + q * 4)) * IN_DIM + i;
        float g = fabsf(wp[0]) + fabsf(wp[IN_DIM]) + fabsf(wp[2 * IN_DIM]) + fabsf(wp[3 * IN_DIM]);
        partial[(size_t)p * IN_DIM + i] = g;
    }
}

// k2: 200 blocks; block = (class c, o-oct). Recompute alpha, scale 8 o-rows.
__global__ __launch_bounds__(256) void k2_alpha_scale(const float* __restrict__ partial,
                                                      const float* __restrict__ w,
                                                      __bf16* __restrict__ wb) {
    int blk = blockIdx.x;        // 0..199
    int c = blk >> 2;
    int o0 = (blk & 3) * 8;
    int i = threadIdx.x;
    float g = 0.f;
#pragma unroll
    for (int q = 0; q < 8; ++q)
        g += partial[(size_t)(c * 8 + q) * IN_DIM + i];
    float m = g;
#pragma unroll
    for (int s = 1; s < 64; s <<= 1) m = fmaxf(m, __shfl_xor(m, s));
    __shared__ float wm[4];
    if ((threadIdx.x & 63) == 0) wm[threadIdx.x >> 6] = m;
    __syncthreads();
    m = fmaxf(fmaxf(wm[0], wm[1]), fmaxf(wm[2], wm[3]));
    float an = __expf((g - m) * INV_T);
    const float* wr = w + ((size_t)c * OUT_DIM + o0) * IN_DIM + i;
    __bf16* wo = wb + ((size_t)c * OUT_DIM + o0) * IN_DIM + i;
#pragma unroll
    for (int o = 0; o < 8; ++o)
        wo[o * IN_DIM] = (__bf16)(wr[o * IN_DIM] * an);
}

// GEMM: out[b, c, o] = sum_i xb[b,i]*wb[c,o,i] + bias[c,o]
// grid = 25 class-PAIRS * 16 row-tiles; block = 4 waves, 512 rows, 2 classes.
// W' slab (32 KB, 64 rows) staged into the union of the 4 waves' Abuf1
// regions (disjoint from Abuf0/chunk0): row r -> lds + (r>>4)*16384 + 8192
// + (r&15)*512. Read into 128 pinned VGPRs, then r7-style chunk pipeline.
// Counted vmcnt: 12 = 8 next-chunk loads + 4 stores (in-order decrement).
// LDS swizzle (both-sides): phys 16B-slot p of row r holds logical p^(r&15).
__global__ __launch_bounds__(256, 2) void gemm(const __bf16* __restrict__ xb,
                                               const __bf16* __restrict__ wb,
                                               const float* __restrict__ bias,
                                               float* __restrict__ out) {
    __shared__ __align__(16) char lds[4 * 2 * 8192];  // 4 waves * {Abuf0, Abuf1}

    int bid = blockIdx.x;
    int cp = bid >> 4;           // 0..24
    int rt = bid & (ROWTILES - 1);
    int c0 = cp * 2;
    int row0 = rt * 512;
    int lane = threadIdx.x & 63;
    int w4 = threadIdx.x >> 6;
    int l15 = lane & 15;
    int g = lane >> 4;
    int s31 = lane & 31;
    int lr = lane >> 5;          // 0/1

    char* Abuf0 = lds + w4 * 16384;
    char* Abuf1 = Abuf0 + 8192;

    // --- stage A chunk 0 (wave-private 16 rows = 8 KB) into Abuf0 ---
    const char* arows = (const char*)(xb + (size_t)(row0 + w4 * 128) * IN_DIM);
#define STAGE_A(BUF, CHUNK)                                                       \
    _Pragma("unroll") for (int il = 0; il < 8; ++il) {                            \
        int r = (CHUNK) * 16 + 2 * il + lr;                                       \
        gload_lds16(arows + (size_t)r * 512 + ((s31 ^ (r & 15)) * 16),            \
                    (BUF) + il * 1024);                                           \
    }
    STAGE_A(Abuf0, 0)

    // --- stage W' pair (32 KB = 64 rows) into the Abuf1 regions ---
    // W row r -> lds + (r>>4)*16384 + 8192 + (r&15)*512 ; instr j covers
    // rows {j*8 + w4*2, +1} (wave-uniform 1 KB dest inside one region).
    const char* wsrc = (const char*)(wb + (size_t)c0 * OUT_DIM * IN_DIM);
#pragma unroll
    for (int j = 0; j < 8; ++j) {
        int re = j * 8 + w4 * 2;               // even row of this instr
        int r = re + lr;                       // this lane's row
        gload_lds16(wsrc + (size_t)r * 512 + ((s31 ^ (r & 15)) * 16),
                    lds + (re >> 4) * 16384 + 8192 + (re & 15) * 512);
    }

    asm volatile("s_waitcnt vmcnt(0)" ::: "memory");
    __syncthreads();
    __builtin_amdgcn_sched_barrier(0);

    // --- W' -> regs (swizzled ds_read); W row ra=ci*32+l15 (+16) ---
    bf16x8 W[2][16];
#pragma unroll
    for (int ci = 0; ci < 2; ++ci)
#pragma unroll
        for (int kk = 0; kk < 8; ++kk) {
            int slot = (4 * kk + g) ^ l15;
            // rows ci*32+l15 -> region 2ci, offset l15*512; +16 -> region 2ci+1
            W[ci][kk]     = *reinterpret_cast<const bf16x8*>(
                lds + (2 * ci) * 16384 + 8192 + l15 * 512 + slot * 16);
            W[ci][8 + kk] = *reinterpret_cast<const bf16x8*>(
                lds + (2 * ci + 1) * 16384 + 8192 + l15 * 512 + slot * 16);
        }
#pragma unroll
    for (int ci = 0; ci < 2; ++ci)
#pragma unroll
        for (int kk = 0; kk < 16; ++kk)
            asm volatile("" : "+v"(W[ci][kk]));
    __builtin_amdgcn_sched_barrier(0);
    __syncthreads();   // all waves done reading W before k=0 stages into Abuf1

    float4 bv00 = *reinterpret_cast<const float4*>(bias + c0 * OUT_DIM + g * 4);
    float4 bv01 = *reinterpret_cast<const float4*>(bias + c0 * OUT_DIM + 16 + g * 4);
    float4 bv10 = *reinterpret_cast<const float4*>(bias + (c0 + 1) * OUT_DIM + g * 4);
    float4 bv11 = *reinterpret_cast<const float4*>(bias + (c0 + 1) * OUT_DIM + 16 + g * 4);

    float* orow = out + (size_t)(row0 + w4 * 128 + l15) * (NCLS * OUT_DIM) + c0 * OUT_DIM + g * 4;

    // --- main loop: 8 chunks of 16 rows, 2 classes each ---
#pragma unroll
    for (int k = 0; k < NCHUNK; ++k) {
        char* cur = (k & 1) ? Abuf1 : Abuf0;
        char* nxt = (k & 1) ? Abuf0 : Abuf1;
        if (k + 1 < NCHUNK) {
            STAGE_A(nxt, k + 1)
            asm volatile("s_waitcnt vmcnt(12)" ::: "memory");
        } else {
            asm volatile("s_waitcnt vmcnt(4)" ::: "memory");
        }
        __builtin_amdgcn_sched_barrier(0);

        f32x4 acc00 = {bv00.x, bv00.y, bv00.z, bv00.w};
        f32x4 acc01 = {bv01.x, bv01.y, bv01.z, bv01.w};
        f32x4 acc10 = {bv10.x, bv10.y, bv10.z, bv10.w};
        f32x4 acc11 = {bv11.x, bv11.y, bv11.z, bv11.w};
#pragma unroll
        for (int kk = 0; kk < 8; ++kk) {
            int slot = (4 * kk + g) ^ l15;
            bf16x8 a = *reinterpret_cast<const bf16x8*>(cur + (size_t)l15 * 512 + slot * 16);
            acc00 = __builtin_amdgcn_mfma_f32_16x16x32_bf16(W[0][kk],     a, acc00, 0, 0, 0);
            acc01 = __builtin_amdgcn_mfma_f32_16x16x32_bf16(W[0][8 + kk], a, acc01, 0, 0, 0);
            acc10 = __builtin_amdgcn_mfma_f32_16x16x32_bf16(W[1][kk],     a, acc10, 0, 0, 0);
            acc11 = __builtin_amdgcn_mfma_f32_16x16x32_bf16(W[1][8 + kk], a, acc11, 0, 0, 0);
        }
        float* op = orow + (size_t)k * 16 * (NCLS * OUT_DIM);
        *reinterpret_cast<f32x4*>(op) = acc00;
        *reinterpret_cast<f32x4*>(op + 16) = acc01;
        *reinterpret_cast<f32x4*>(op + OUT_DIM) = acc10;
        *reinterpret_cast<f32x4*>(op + OUT_DIM + 16) = acc11;
    }
#undef STAGE_A
}

extern "C" void kernel_launch(void* const* d_in, const int* in_sizes, int n_in,
                              void* d_out, int out_size, void* d_ws, size_t ws_size,
                              hipStream_t stream) {
    const float* x    = (const float*)d_in[0];
    const float* w    = (const float*)d_in[1];
    const float* bias = (const float*)d_in[2];
    float* out = (float*)d_out;

    __bf16* xb      = (__bf16*)d_ws;                                   // 4 MB
    __bf16* wb      = xb + (size_t)B_ROWS * IN_DIM;                    // 0.8 MB
    float*  partial = (float*)(wb + (size_t)NCLS * OUT_DIM * IN_DIM);  // 400 KB

    k1_cvt_partial<<<CVT_BLOCKS + PG_BLOCKS, 256, 0, stream>>>(x, w, xb, partial);
    k2_alpha_scale<<<200, 256, 0, stream>>>(partial, w, wb);
    gemm<<<25 * ROWTILES, 256, 0, stream>>>(xb, wb, bias, out);
}